// Round 6
// baseline (198.479 us; speedup 1.0000x reference)
//
#include <hip/hip_runtime.h>
#include <stdint.h>

typedef unsigned int u32;
typedef unsigned short u16;

#define N_  1024
#define F_  512
#define ALPHA 0.2f
#define TSTR 68   // transpose tile stride (u16): 136 B rows -> uint2-aligned reads, ~4-way write conflicts

typedef __attribute__((ext_vector_type(8))) short short8;
typedef __attribute__((ext_vector_type(4))) float float4v;

union Frag { short8 s; u32 u[4]; };

static __device__ __forceinline__ float bits2f(u32 b){ union{u32 u; float f;} c; c.u=b; return c.f; }
static __device__ __forceinline__ u32   f2bits(float f){ union{float f_; u32 u;} c; c.f_=f; return c.u; }
static __device__ __forceinline__ float bflo(u32 p){ return bits2f(p<<16); }
static __device__ __forceinline__ float bfhi(u32 p){ return bits2f(p & 0xffff0000u); }
static __device__ __forceinline__ u32   f2bf(float f){ u32 u=f2bits(f); return (u + 0x7fffu + ((u>>16)&1u))>>16; }
static __device__ __forceinline__ u32   cvt_pk_bf16(float lo, float hi){
    u32 r; asm("v_cvt_pk_bf16_f32 %0, %1, %2" : "=v"(r) : "v"(lo), "v"(hi)); return r;
}

// async global->LDS, 16 B per lane; LDS dest = wave-uniform base + lane*16
static __device__ __forceinline__ void gload_lds16(const void* g, void* l){
    __builtin_amdgcn_global_load_lds((const __attribute__((address_space(1))) u32*)g,
                                     (__attribute__((address_space(3))) u32*)l, 16, 0, 0);
}

// ---- kernel 1 (fused prep): w1/w2 + transpose X->XT bf16 + d1/d2 dots ----
// grid (16,16) = 256 blocks = 1/CU, 1024 threads = 16 waves.
// Phase A: each block computes w1 = W^T a1, w2 = W^T a2 (512 f each) into LDS.
//   o-range split across thread halves (t<512: o 0..255 for f=t&511; t>=512: o 256..511),
//   reduced in LDS. W is 1 MB -> L2/L3 resident across the 256 blocks.
// Phase B: 8 f-slices of 64: read X float4 coalesced, bf16-convert into double-buffered
//   64x64 transpose tile (1 barrier/slice), write XT [b][f][m] coalesced (uint2 = 4 m),
//   accumulate d1 += X.w1, d2 += X.w2 in-register across all slices.
// Epilogue: shfl-reduce d1/d2 over the 16 f-lanes, plain stores (no atomics, no memset).
// XCD-affinity decode matches k_main so XT[b] is produced in the consuming XCD's L2.
__global__ __launch_bounds__(1024)
void k_prep(const float* __restrict__ X, const float* __restrict__ W,
            const float* __restrict__ a1, const float* __restrict__ a2,
            u16* __restrict__ XT, float* __restrict__ d1acc, float* __restrict__ d2acc){
    __shared__ float wls[2][1024];     // [half][w1 512 | w2 512] partials -> wls[0] = final
    __shared__ u16 tile[2][64*TSTR];   // double-buffered transpose tile (17.4 KB)

    const int t  = threadIdx.x;
    const int id   = blockIdx.x + (blockIdx.y << 4);
    const int xcd  = id & 7, slot = id >> 3;
    const int b    = (xcd << 1) | (slot >> 4);
    const int m0   = (slot & 15) << 6;

    // ---- Phase A ----
    {
        const int half = t >> 9, ff = t & 511;
        float s1 = 0.f, s2 = 0.f;
        const int o0 = half * 256;
        #pragma unroll 4
        for(int o = o0; o < o0 + 256; o++){
            float wv = W[o*F_ + ff];
            s1 += wv * a1[o];
            s2 += wv * a2[o];
        }
        wls[half][ff]     = s1;
        wls[half][512+ff] = s2;
    }
    __syncthreads();
    wls[0][t] += wls[1][t];            // w1 | w2 finalized in wls[0]
    __syncthreads();

    // ---- Phase B ----
    const int ml  = t >> 4;            // 0..63: m-row
    const int fl4 = (t & 15) * 4;      // f within slice
    const int ml4 = (t & 15) * 4;      // read side: m-quad
    float d1p = 0.f, d2p = 0.f;
    const float* Xrow = X + ((size_t)(b*N_ + m0 + ml))*F_;

    for(int s = 0; s < 8; s++){
        const int f0 = s * 64;
        float4 w1q = *(const float4*)&wls[0][f0 + fl4];
        float4 w2q = *(const float4*)&wls[0][512 + f0 + fl4];
        u16* tl = tile[s & 1];

        float4 v = *(const float4*)(Xrow + f0 + fl4);
        tl[(fl4+0)*TSTR + ml] = (u16)f2bf(v.x);
        tl[(fl4+1)*TSTR + ml] = (u16)f2bf(v.y);
        tl[(fl4+2)*TSTR + ml] = (u16)f2bf(v.z);
        tl[(fl4+3)*TSTR + ml] = (u16)f2bf(v.w);
        d1p += v.x*w1q.x + v.y*w1q.y + v.z*w1q.z + v.w*w1q.w;
        d2p += v.x*w2q.x + v.y*w2q.y + v.z*w2q.z + v.w*w2q.w;

        __syncthreads();               // tile[s&1] complete (next slice uses other buffer)

        const int f = f0 + (t >> 4);   // 64 f-rows, 16 m-quads
        uint2 val = *(const uint2*)(&tl[(t>>4)*TSTR + ml4]);
        *(uint2*)(XT + ((size_t)(b*F_ + f))*N_ + m0 + ml4) = val;
    }

    // ---- epilogue: reduce d1/d2 over the 16 f-lanes of each row ----
    d1p += __shfl_xor(d1p, 1, 64);  d2p += __shfl_xor(d2p, 1, 64);
    d1p += __shfl_xor(d1p, 2, 64);  d2p += __shfl_xor(d2p, 2, 64);
    d1p += __shfl_xor(d1p, 4, 64);  d2p += __shfl_xor(d2p, 4, 64);
    d1p += __shfl_xor(d1p, 8, 64);  d2p += __shfl_xor(d2p, 8, 64);
    if((t & 15) == 0){
        d1acc[b*N_ + m0 + ml] = d1p;
        d2acc[b*N_ + m0 + ml] = d2p;
    }
}

// ---- kernel 2: fused scores+softmax+PV+ELU, producer/consumer, 16 waves ----
// (UNCHANGED from round 5 — 66 us known-good)
__global__ __launch_bounds__(1024, 4)
void k_main(const u16* __restrict__ XT, const int* __restrict__ adj,
            const float* __restrict__ d1acc, const float* __restrict__ d2acc,
            float* __restrict__ out){
    __shared__ u16 xbuf[3][2][8192];   // 96 KB triple-buffered X tiles
    __shared__ u32 lds_e2[N_];         // 4 KB exp(f2)/exp(.2 f2) bf16-pair table
    __shared__ u16 pbuf[2][4][512];    // 8 KB P A-fragments [buf][nsub][lane*8]
    __shared__ float dsums[64];        // row softmax denominators

    const int t    = threadIdx.x;
    const int lane = t & 63;
    const int wv   = t >> 6;           // 0..15
    const int nsub = wv & 3;           // consumer: row-group of 16
    const int fq   = wv >> 2;          // consumer: f-quarter of 128
    const int id   = blockIdx.x + (blockIdx.y << 4);
    const int xcd  = id & 7, slot = id >> 3;
    const int b    = (xcd << 1) | (slot >> 4);
    const int n0   = (slot & 15) << 6;
    const int r16  = lane & 15;
    const int quad = lane >> 4;
    const int rowL = lane >> 4;        // producer: row 0..3 within wave's quartet
    const int qL   = lane & 15;        // producer: col-pair index (cols qL*2, qL*2+1)

    // exp(f2)/exp(.2*f2) bf16-pair table: 1 entry/thread
    {
        float dv = d2acc[(size_t)b*N_ + t];
        lds_e2[t] = f2bf(__expf(dv)) | (f2bf(__expf(ALPHA*dv))<<16);
    }
    const float d1v  = d1acc[b*N_ + n0 + wv*4 + rowL];
    const float e1pL = __expf(d1v);
    const float e1nL = __expf(ALPHA*d1v);
    const int* adjLane = adj + ((size_t)(b*N_ + n0 + wv*4 + rowL))*N_ + qL*2;
    const u16* XTb = XT + (size_t)b*F_*N_;

    float dsum = 0.f;
    const int pOff = ((wv&3)*4 + rowL + (qL>>2)*16)*8 + (qL&3)*2;

    auto produce = [&](int c, int pb, int2 ad){
        uint2 ev = *(const uint2*)(&lds_e2[c*32 + qL*2]);
        float p0 = fmaxf(e1pL*bflo(ev.x), e1nL*bfhi(ev.x)); p0 = ad.x ? p0 : 0.f;
        float p1 = fmaxf(e1pL*bflo(ev.y), e1nL*bfhi(ev.y)); p1 = ad.y ? p1 : 0.f;
        dsum += p0 + p1;
        *(u32*)(&pbuf[pb][wv>>2][pOff]) = cvt_pk_bf16(p0, p1);
    };
    auto stage = [&](int mcol, u16 (*buf)[8192]){
        #pragma unroll
        for(int k=0;k<2;k++){
            int idx = wv*2 + k, fhh = idx>>4, c = idx&15;
            const u16* g = XTb + (size_t)(fhh*256 + c*16 + r16)*N_ + mcol + quad*8;
            gload_lds16(g, &buf[fhh][c*512]);
        }
    };

    __syncthreads();                       // lds_e2 ready
    { int2 ad0 = *(const int2*)(adjLane); produce(0, 0, ad0); }
    stage(0,  xbuf[0]);
    int2 adU = *(const int2*)(adjLane + 32);   // adj chunk 1
    stage(32, xbuf[1]);
    asm volatile("s_waitcnt lgkmcnt(0)" ::: "memory");
    __syncthreads();                       // P[0] + chunks 0,1 resident (full drain, one-time)

    float4v acc[8];
    #pragma unroll
    for(int i=0;i<8;i++) acc[i] = (float4v){0.f,0.f,0.f,0.f};

    int db = 0;
    for(int i=0;i<32;i++){
        asm volatile("s_waitcnt vmcnt(2) lgkmcnt(0)\n\ts_barrier" ::: "memory");

        // body VMEM (uniform 3/wave): adj chunk i+2, stage chunk i+2 (dummies wrap at tail)
        const int ms = (i*32 + 64) & (N_-1);
        int2 adV = *(const int2*)(adjLane + ms);
        int dbw = db + 2; if(dbw >= 3) dbw -= 3;
        stage(ms, xbuf[dbw]);

        if(i < 31) produce(i+1, (i+1)&1, adU);   // P[i+1] from adj[i+1] (loaded last body)

        Frag af;
        { uint4 aw = *(const uint4*)(&pbuf[i&1][nsub][lane*8]);
          af.u[0]=aw.x; af.u[1]=aw.y; af.u[2]=aw.z; af.u[3]=aw.w; }
        const u16* bb = &xbuf[db][fq>>1][(fq&1)*8*512 + lane*8];   // lane-linear ds_read_b128
        #pragma unroll
        for(int ct=0; ct<8; ct++){
            uint4 bw = *(const uint4*)(bb + ct*512);
            Frag bf_; bf_.u[0]=bw.x; bf_.u[1]=bw.y; bf_.u[2]=bw.z; bf_.u[3]=bw.w;
            acc[ct] = __builtin_amdgcn_mfma_f32_16x16x32_bf16(af.s, bf_.s, acc[ct], 0, 0, 0);
        }
        adU = adV;
        db = (db==2) ? 0 : db+1;
    }

    // ---- softmax denominators: reduce over qL (lane bits 0..3), one value per row ----
    asm volatile("s_waitcnt vmcnt(0) lgkmcnt(0)" ::: "memory");   // drain tail dummy DMAs
    dsum += __shfl_xor(dsum, 1, 64);
    dsum += __shfl_xor(dsum, 2, 64);
    dsum += __shfl_xor(dsum, 4, 64);
    dsum += __shfl_xor(dsum, 8, 64);
    if(qL == 0) dsums[wv*4 + rowL] = dsum;
    __syncthreads();
    float invr[4];
    #pragma unroll
    for(int r=0;r<4;r++) invr[r] = 1.0f / fmaxf(dsums[nsub*16 + quad*4 + r], 1e-30f);

    // ---- epilogue: scale, ELU, fp32 store ----
    #pragma unroll
    for(int ct=0; ct<8; ct++){
        #pragma unroll
        for(int r=0;r<4;r++){
            float v = acc[ct][r] * invr[r];
            v = (v > 0.f) ? v : (__expf(v) - 1.f);
            int n_out = n0 + nsub*16 + quad*4 + r;
            out[((size_t)(b*N_ + n_out))*F_ + fq*128 + ct*16 + r16] = v;
        }
    }
}

extern "C" void kernel_launch(void* const* d_in, const int* in_sizes, int n_in,
                              void* d_out, int out_size, void* d_ws, size_t ws_size,
                              hipStream_t stream) {
    const float* X  = (const float*)d_in[0];   // [16,1024,512] fp32
    const int* adj  = (const int*)d_in[1];     // [16,1024,1024] int32
    const float* W  = (const float*)d_in[2];   // [512,512] fp32
    const float* a1 = (const float*)d_in[3];   // [512]
    const float* a2 = (const float*)d_in[4];   // [512]
    float* out = (float*)d_out;                // [16,1024,512] fp32

    float* ws    = (float*)d_ws;
    float* d1acc = ws + 1024;                  // fully written by k_prep (no memset needed)
    float* d2acc = ws + 1024 + 16384;
    u16*  XT     = (u16*)(ws + 50176);         // 16.78 MB bf16 [b][f][m]

    k_prep<<<dim3(16, 16), 1024, 0, stream>>>(X, W, a1, a2, XT, d1acc, d2acc);
    k_main<<<dim3(16, 16), 1024, 0, stream>>>(XT, adj, d1acc, d2acc, out);
}